// Round 13
// baseline (49.845 us; speedup 1.0000x reference)
//
#include <hip/hip_runtime.h>
#include <hip/hip_bf16.h>

#define TT 8192
#define DD 64
#define NTILE 64                        // 8192 / 128
#define NBLK (NTILE * (NTILE + 1) / 2)  // 2080 upper-tri 128x128 tiles
#define GRID 1024                       // exactly-resident persistent grid
#define NPREP 256                       // prep blocks (32 rows each)
#define L2E 1.4426950408889634f

typedef __attribute__((ext_vector_type(8))) short short8;
typedef __attribute__((ext_vector_type(4))) float f32x4;

static __device__ __forceinline__ float fast_exp2(float x) {
#if __has_builtin(__builtin_amdgcn_exp2f)
    return __builtin_amdgcn_exp2f(x);
#else
    float r; asm volatile("v_exp_f32 %0, %1" : "=v"(r) : "v"(x)); return r;
#endif
}

static __device__ __forceinline__ void decode_tri(int k, int& tr, int& tc) {
    int t = (int)((129.0f - sqrtf(16641.0f - 8.0f * (float)k)) * 0.5f);
    while (t * NTILE - t * (t - 1) / 2 > k) --t;
    while ((t + 1) * NTILE - (t + 1) * t / 2 <= k) ++t;
    tr = t;
    tc = t + (k - (t * NTILE - t * (t - 1) / 2));
}

// Fragment-ready layout: for rowgroup rg = row/16, ks = k/32:
//   flat elem index = (rg*2 + ks)*512 + ((k%32)/8)*128 + (row%16)*8 + (k%8)
// A wave's MFMA fragment load for (rg, ks) is xf_base + lane*8 elems --
// one contiguous 1 KB burst per instruction.
//
// ws layout:
//   [0]        float sq2[8192]     (L2E * ||x_i||^2)
//   [+32KB]    short xf[8192*64]   (1 MB, fragment-tiled bf16)
//   [+32KB+1MB]float p1[1024]; float p3[256]

__global__ __launch_bounds__(256) void prep_kernel(const float* __restrict__ x,
                                                   float* __restrict__ sq2,
                                                   short* __restrict__ xf,
                                                   float* __restrict__ p3) {
    const int tid = threadIdx.x;
    const int r   = tid >> 3;           // 0..31 row within block
    const int ch  = tid & 7;            // 0..7, 8-element k-chunk
    const int row = blockIdx.x * 32 + r;

    const float4 u = *(const float4*)(x + (size_t)row * DD + ch * 8);
    const float4 v = *(const float4*)(x + (size_t)row * DD + ch * 8 + 4);
    short8 s8;
    s8[0] = __builtin_bit_cast(short, __float2bfloat16(u.x));
    s8[1] = __builtin_bit_cast(short, __float2bfloat16(u.y));
    s8[2] = __builtin_bit_cast(short, __float2bfloat16(u.z));
    s8[3] = __builtin_bit_cast(short, __float2bfloat16(u.w));
    s8[4] = __builtin_bit_cast(short, __float2bfloat16(v.x));
    s8[5] = __builtin_bit_cast(short, __float2bfloat16(v.y));
    s8[6] = __builtin_bit_cast(short, __float2bfloat16(v.z));
    s8[7] = __builtin_bit_cast(short, __float2bfloat16(v.w));

    const size_t F = (size_t)(row >> 4) * 1024 + (size_t)(ch >> 2) * 512
                   + (size_t)(ch & 3) * 128 + (size_t)(row & 15) * 8;
    *(short8*)(xf + F) = s8;

    float s = u.x*u.x + u.y*u.y + u.z*u.z + u.w*u.w
            + v.x*v.x + v.y*v.y + v.z*v.z + v.w*v.w;
    s += __shfl_xor(s, 1, 64);
    s += __shfl_xor(s, 2, 64);
    s += __shfl_xor(s, 4, 64);

    __shared__ float e3[32];
    if (ch == 0) {
        sq2[row] = L2E * s;
        e3[r] = __expf(s);
    }
    __syncthreads();
    if (tid == 0) {
        float t = 0.f;
        #pragma unroll
        for (int i = 0; i < 32; i++) t += e3[i];
        p3[blockIdx.x] = t;
    }
}

// Persistent: 1024 blocks x 256 thr (4 waves = one 128x128 tile per iter).
// Loop k = sbid, sbid+1024, ... ; per-iter order MFMA -> next-loads -> epilogue
// so the exp epilogue covers the next tile's load latency.
__global__ __launch_bounds__(256, 4) void mmd_main(const short* __restrict__ xf,
                                                   const float* __restrict__ sq2,
                                                   float* __restrict__ p1) {
    const int bid  = blockIdx.x;
    const int sbid = (bid & 7) * (GRID / 8) + (bid >> 3);   // XCD band swizzle
    const int wid  = threadIdx.x >> 6;
    const int lane = threadIdx.x & 63;
    const int wr = wid >> 1, wc = wid & 1;      // 2x2 wave grid, 64x64 per wave
    const int crow0 = (lane >> 4) * 4;          // C/D: row=(lane>>4)*4+reg, col=lane&15
    const int ccol  = lane & 15;

    float local = 0.f;

    int k = sbid;
    int tr, tc;
    decode_tri(k, tr, tc);

    short8 a[2][4], b[2][4];
    float sqrl[16], sqcl[4];

#define LOAD_FRAGS(TRR, TCC)                                                          \
    { const short* baseA = xf + (size_t)((TRR) * 16 + wr * 8) * 512 + lane * 8;       \
      const short* baseB = xf + (size_t)((TCC) * 16 + wc * 8) * 512 + lane * 8;       \
      _Pragma("unroll")                                                               \
      for (int ks = 0; ks < 2; ks++)                                                  \
          _Pragma("unroll")                                                           \
          for (int m = 0; m < 4; m++)                                                 \
              a[ks][m] = *(const short8*)(baseA + (m * 2 + ks) * 512);                \
      _Pragma("unroll")                                                               \
      for (int ks = 0; ks < 2; ks++)                                                  \
          _Pragma("unroll")                                                           \
          for (int n = 0; n < 4; n++)                                                 \
              b[ks][n] = *(const short8*)(baseB + (n * 2 + ks) * 512); }

#define LOAD_SQ(TRR, TCC)                                                             \
    { _Pragma("unroll")                                                               \
      for (int m = 0; m < 4; m++) {                                                   \
          const float4 f = *(const float4*)(sq2 + (TRR) * 128 + wr * 64 + m * 16 + crow0); \
          sqrl[4*m+0] = f.x; sqrl[4*m+1] = f.y; sqrl[4*m+2] = f.z; sqrl[4*m+3] = f.w; \
      }                                                                               \
      _Pragma("unroll")                                                               \
      for (int n = 0; n < 4; n++)                                                     \
          sqcl[n] = sq2[(TCC) * 128 + wc * 64 + n * 16 + ccol]; }

    LOAD_FRAGS(tr, tc);
    LOAD_SQ(tr, tc);

    while (true) {
        f32x4 c[4][4];
        #pragma unroll
        for (int m = 0; m < 4; m++)
            #pragma unroll
            for (int n = 0; n < 4; n++)
                c[m][n] = (f32x4){0.f, 0.f, 0.f, 0.f};

        #pragma unroll
        for (int ks = 0; ks < 2; ks++)
            #pragma unroll
            for (int m = 0; m < 4; m++)
                #pragma unroll
                for (int n = 0; n < 4; n++)
                    c[m][n] = __builtin_amdgcn_mfma_f32_16x16x32_bf16(a[ks][m], b[ks][n], c[m][n], 0, 0, 0);

        // prefetch next tile's fragments (WAR on frag regs is safe post-MFMA-issue;
        // the exp epilogue below covers their latency)
        const int kn = k + GRID;
        const bool more = (kn < NBLK);
        int trn = 0, tcn = 0;
        if (more) {
            decode_tri(kn, trn, tcn);
            LOAD_FRAGS(trn, tcn);
        }

        // epilogue: sum exp2(L2E*sq_r + L2E*sq_c - 2*L2E*g) for current tile
        const float w = (tr == tc) ? 1.0f : 2.0f;
        float acc4[4] = {0.f, 0.f, 0.f, 0.f};
        #pragma unroll
        for (int n = 0; n < 4; n++)
            #pragma unroll
            for (int m = 0; m < 4; m++)
                #pragma unroll
                for (int r = 0; r < 4; r++)
                    acc4[r] += fast_exp2(fmaf(-2.0f * L2E, c[m][n][r], sqrl[m * 4 + r] + sqcl[n]));
        local += ((acc4[0] + acc4[1]) + (acc4[2] + acc4[3])) * w;

        if (!more) break;
        LOAD_SQ(trn, tcn);
        k = kn; tr = trn; tc = tcn;
    }
#undef LOAD_FRAGS
#undef LOAD_SQ

    #pragma unroll
    for (int off = 32; off; off >>= 1) local += __shfl_down(local, off, 64);
    __shared__ float red[4];
    if (lane == 0) red[wid] = local;
    __syncthreads();
    if (threadIdx.x == 0)
        p1[bid] = red[0] + red[1] + red[2] + red[3];
}

__global__ void finalize_kernel(const float* __restrict__ p1, const float* __restrict__ p3,
                                float* __restrict__ out) {
    const int lane = threadIdx.x & 63;
    const int wid  = threadIdx.x >> 6;
    float s1 = 0.f, s3 = 0.f;
    for (int i = threadIdx.x; i < GRID; i += 256) s1 += p1[i];
    for (int i = threadIdx.x; i < NPREP; i += 256) s3 += p3[i];
    #pragma unroll
    for (int off = 32; off; off >>= 1) {
        s1 += __shfl_down(s1, off, 64);
        s3 += __shfl_down(s3, off, 64);
    }
    __shared__ float r1[4], r3[4];
    if (lane == 0) { r1[wid] = s1; r3[wid] = s3; }
    __syncthreads();
    if (threadIdx.x == 0) {
        const float t1 = (r1[0] + r1[1] + r1[2] + r1[3]) / ((float)TT * (float)TT);
        const float t3 = (r3[0] + r3[1] + r3[2] + r3[3]) / (float)TT;
        out[0] = t1 + 1.0f + t3;
    }
}

extern "C" void kernel_launch(void* const* d_in, const int* in_sizes, int n_in,
                              void* d_out, int out_size, void* d_ws, size_t ws_size,
                              hipStream_t stream) {
    const float* x = (const float*)d_in[0];   // xs: [4, 8192, 64] f32; only batch 0 used
    float* out = (float*)d_out;
    char* ws = (char*)d_ws;

    float* sq2 = (float*)ws;
    short* xf = (short*)(ws + TT * sizeof(float));
    float* p1 = (float*)(ws + TT * sizeof(float) + (size_t)TT * DD * sizeof(short));
    float* p3 = p1 + GRID;

    prep_kernel<<<NPREP, 256, 0, stream>>>(x, sq2, xf, p3);
    mmd_main<<<GRID, 256, 0, stream>>>(xf, sq2, p1);
    finalize_kernel<<<1, 256, 0, stream>>>(p1, p3, out);
}

// Round 14
// 25.925 us; speedup vs baseline: 1.9226x; 1.9226x over previous
//
#include <hip/hip_runtime.h>
#include <hip/hip_bf16.h>

#define TT 8192
#define DD 64
#define NTILE 64                        // 8192 / 128
#define NBLK (NTILE * (NTILE + 1) / 2)  // 2080 upper-tri 128x128 tiles
#define NPAIR (NBLK / 2)                // 1040 blocks, 2 tiles each
#define NXCD 8
#define NPREP 256                       // prep blocks (32 rows each)
#define L2E 1.4426950408889634f

typedef __attribute__((ext_vector_type(8))) short short8;
typedef __attribute__((ext_vector_type(4))) float f32x4;

static __device__ __forceinline__ float fast_exp2(float x) {
#if __has_builtin(__builtin_amdgcn_exp2f)
    return __builtin_amdgcn_exp2f(x);
#else
    float r; asm volatile("v_exp_f32 %0, %1" : "=v"(r) : "v"(x)); return r;
#endif
}

static __device__ __forceinline__ void decode_tri(int k, int& tr, int& tc) {
    int t = (int)((129.0f - sqrtf(16641.0f - 8.0f * (float)k)) * 0.5f);
    while (t * NTILE - t * (t - 1) / 2 > k) --t;
    while ((t + 1) * NTILE - (t + 1) * t / 2 <= k) ++t;
    tr = t;
    tc = t + (k - (t * NTILE - t * (t - 1) / 2));
}

// Fragment-ready layout: for rowgroup rg = row/16, ks = k/32:
//   flat elem index = (rg*2 + ks)*512 + ((k%32)/8)*128 + (row%16)*8 + (k%8)
// Panel for tile-row t = 8 rowgroups = 8192 contiguous shorts (16 KB) at xf + t*8192.
//
// ws layout:
//   [0]        float sq2[8192]     (L2E * ||x_i||^2)
//   [+32KB]    short xf[8192*64]   (1 MB, fragment-tiled bf16)
//   [+32KB+1MB]float p1[1040]; float p3[256]

__global__ __launch_bounds__(256) void prep_kernel(const float* __restrict__ x,
                                                   float* __restrict__ sq2,
                                                   short* __restrict__ xf,
                                                   float* __restrict__ p3) {
    const int tid = threadIdx.x;
    const int r   = tid >> 3;           // 0..31 row within block
    const int ch  = tid & 7;            // 0..7, 8-element k-chunk
    const int row = blockIdx.x * 32 + r;

    const float4 u = *(const float4*)(x + (size_t)row * DD + ch * 8);
    const float4 v = *(const float4*)(x + (size_t)row * DD + ch * 8 + 4);
    short8 s8;
    s8[0] = __builtin_bit_cast(short, __float2bfloat16(u.x));
    s8[1] = __builtin_bit_cast(short, __float2bfloat16(u.y));
    s8[2] = __builtin_bit_cast(short, __float2bfloat16(u.z));
    s8[3] = __builtin_bit_cast(short, __float2bfloat16(u.w));
    s8[4] = __builtin_bit_cast(short, __float2bfloat16(v.x));
    s8[5] = __builtin_bit_cast(short, __float2bfloat16(v.y));
    s8[6] = __builtin_bit_cast(short, __float2bfloat16(v.z));
    s8[7] = __builtin_bit_cast(short, __float2bfloat16(v.w));

    const size_t F = (size_t)(row >> 4) * 1024 + (size_t)(ch >> 2) * 512
                   + (size_t)(ch & 3) * 128 + (size_t)(row & 15) * 8;
    *(short8*)(xf + F) = s8;

    float s = u.x*u.x + u.y*u.y + u.z*u.z + u.w*u.w
            + v.x*v.x + v.y*v.y + v.z*v.z + v.w*v.w;
    s += __shfl_xor(s, 1, 64);
    s += __shfl_xor(s, 2, 64);
    s += __shfl_xor(s, 4, 64);

    __shared__ float e3[32];
    if (ch == 0) {
        sq2[row] = L2E * s;
        e3[r] = __expf(s);
    }
    __syncthreads();
    if (tid == 0) {
        float t = 0.f;
        #pragma unroll
        for (int i = 0; i < 32; i++) t += e3[i];
        p3[blockIdx.x] = t;
    }
}

// 512 thr = 8 waves: waves 0-3 tile 2s, waves 4-7 tile 2s+1 (64x64 quadrants).
// The 4 fragment panels (A0,B0,A1,B1; 16 KB each) + 4x128 norm rows are staged
// into LDS cooperatively, then all fragment reads are conflict-free ds_read_b128.
__global__ __launch_bounds__(512, 4) void mmd_main(const short* __restrict__ xf,
                                                   const float* __restrict__ sq2,
                                                   float* __restrict__ p1) {
    const int s = (blockIdx.x % NXCD) * (NPAIR / NXCD) + blockIdx.x / NXCD;
    const int k0 = s * 2;
    int tr0, tc0, tr1, tc1;
    decode_tri(k0, tr0, tc0);
    decode_tri(k0 + 1, tr1, tc1);

    const int tid  = threadIdx.x;
    const int wid  = tid >> 6;          // 0..7
    const int lane = tid & 63;

    __shared__ short sfrag[4 * 8192];   // 64 KB: panels A0,B0,A1,B1
    __shared__ float lsq[4 * 128];      // 2 KB: norms for rows of tr0,tc0,tr1,tc1
    __shared__ float red[8];

    // ---- cooperative staging: 64 chunks of 1 KB; wave w stages chunks w+8j ----
    const short* gA0 = xf + (size_t)tr0 * 8192;
    const short* gB0 = xf + (size_t)tc0 * 8192;
    const short* gA1 = xf + (size_t)tr1 * 8192;
    const short* gB1 = xf + (size_t)tc1 * 8192;

    short8 v[8];
    #pragma unroll
    for (int j = 0; j < 8; j++) {
        const int p = j >> 1;                        // compile-time panel index
        const int sub = wid + 8 * (j & 1);           // sub-chunk within panel
        const short* base = (p == 0) ? gA0 : (p == 1) ? gB0 : (p == 2) ? gA1 : gB1;
        v[j] = *(const short8*)(base + sub * 512 + lane * 8);
    }
    {
        const int rowblk = (tid < 128) ? tr0 : (tid < 256) ? tc0 : (tid < 384) ? tr1 : tc1;
        lsq[tid] = sq2[rowblk * 128 + (tid & 127)];
    }
    #pragma unroll
    for (int j = 0; j < 8; j++)
        *(short8*)(&sfrag[(wid + 8 * j) * 512 + lane * 8]) = v[j];
    __syncthreads();

    // ---- compute ----
    const int wTile = wid >> 2;                      // 0 or 1
    const int quad  = wid & 3;
    const int wr = quad >> 1, wc = quad & 1;         // 64x64 quadrant
    const int crow0 = (lane >> 4) * 4;               // C/D: row=(lane>>4)*4+reg
    const int ccol  = lane & 15;                     //      col=lane&15
    const int slotA = wTile * 2, slotB = wTile * 2 + 1;

    f32x4 c[4][4];
    #pragma unroll
    for (int m = 0; m < 4; m++)
        #pragma unroll
        for (int n = 0; n < 4; n++)
            c[m][n] = (f32x4){0.f, 0.f, 0.f, 0.f};

    #pragma unroll
    for (int ks = 0; ks < 2; ks++) {
        short8 a[4], b[4];
        #pragma unroll
        for (int m = 0; m < 4; m++)
            a[m] = *(const short8*)(&sfrag[slotA * 8192 + (wr * 8 + m * 2 + ks) * 512 + lane * 8]);
        #pragma unroll
        for (int n = 0; n < 4; n++)
            b[n] = *(const short8*)(&sfrag[slotB * 8192 + (wc * 8 + n * 2 + ks) * 512 + lane * 8]);
        #pragma unroll
        for (int m = 0; m < 4; m++)
            #pragma unroll
            for (int n = 0; n < 4; n++)
                c[m][n] = __builtin_amdgcn_mfma_f32_16x16x32_bf16(a[m], b[n], c[m][n], 0, 0, 0);
    }

    const int trW = wTile ? tr1 : tr0;
    const int tcW = wTile ? tc1 : tc0;
    const float w = (trW == tcW) ? 1.0f : 2.0f;

    // epilogue: sum exp2(L2E*sq_r + L2E*sq_c - 2*L2E*g); norms read from LDS
    float acc4[4] = {0.f, 0.f, 0.f, 0.f};
    #pragma unroll
    for (int n = 0; n < 4; n++) {
        const float sqc = lsq[slotB * 128 + wc * 64 + n * 16 + ccol];
        #pragma unroll
        for (int m = 0; m < 4; m++) {
            const f32x4 f = *(const f32x4*)(&lsq[slotA * 128 + wr * 64 + m * 16 + crow0]);
            #pragma unroll
            for (int r = 0; r < 4; r++)
                acc4[r] += fast_exp2(fmaf(-2.0f * L2E, c[m][n][r], f[r] + sqc));
        }
    }

    float local = ((acc4[0] + acc4[1]) + (acc4[2] + acc4[3])) * w;
    #pragma unroll
    for (int off = 32; off; off >>= 1) local += __shfl_down(local, off, 64);
    if (lane == 0) red[wid] = local;
    __syncthreads();
    if (tid == 0) {
        float t = 0.f;
        #pragma unroll
        for (int i = 0; i < 8; i++) t += red[i];
        p1[s] = t;
    }
}

__global__ void finalize_kernel(const float* __restrict__ p1, const float* __restrict__ p3,
                                float* __restrict__ out) {
    const int lane = threadIdx.x & 63;
    const int wid  = threadIdx.x >> 6;
    float s1 = 0.f, s3 = 0.f;
    for (int i = threadIdx.x; i < NPAIR; i += 256) s1 += p1[i];
    for (int i = threadIdx.x; i < NPREP; i += 256) s3 += p3[i];
    #pragma unroll
    for (int off = 32; off; off >>= 1) {
        s1 += __shfl_down(s1, off, 64);
        s3 += __shfl_down(s3, off, 64);
    }
    __shared__ float r1[4], r3[4];
    if (lane == 0) { r1[wid] = s1; r3[wid] = s3; }
    __syncthreads();
    if (threadIdx.x == 0) {
        const float t1 = (r1[0] + r1[1] + r1[2] + r1[3]) / ((float)TT * (float)TT);
        const float t3 = (r3[0] + r3[1] + r3[2] + r3[3]) / (float)TT;
        out[0] = t1 + 1.0f + t3;
    }
}

extern "C" void kernel_launch(void* const* d_in, const int* in_sizes, int n_in,
                              void* d_out, int out_size, void* d_ws, size_t ws_size,
                              hipStream_t stream) {
    const float* x = (const float*)d_in[0];   // xs: [4, 8192, 64] f32; only batch 0 used
    float* out = (float*)d_out;
    char* ws = (char*)d_ws;

    float* sq2 = (float*)ws;
    short* xf = (short*)(ws + TT * sizeof(float));
    float* p1 = (float*)(ws + TT * sizeof(float) + (size_t)TT * DD * sizeof(short));
    float* p3 = p1 + NPAIR;

    prep_kernel<<<NPREP, 256, 0, stream>>>(x, sq2, xf, p3);
    mmd_main<<<NPAIR, 512, 0, stream>>>(xf, sq2, p1);
    finalize_kernel<<<1, 256, 0, stream>>>(p1, p3, out);
}

// Round 15
// 23.651 us; speedup vs baseline: 2.1075x; 1.0962x over previous
//
#include <hip/hip_runtime.h>
#include <hip/hip_bf16.h>

#define TT 8192
#define DD 64
#define NTILE 64                        // 8192 / 128
#define NBLK (NTILE * (NTILE + 1) / 2)  // 2080 upper-tri 128x128 tiles
#define NPAIR (NBLK / 2)                // 1040 blocks, 2 tiles each
#define NXCD 8
#define NPREP 256                       // prep blocks (32 rows each)
#define L2E 1.4426950408889634f

typedef __attribute__((ext_vector_type(8))) short short8;
typedef __attribute__((ext_vector_type(4))) float f32x4;

static __device__ __forceinline__ float fast_exp2(float x) {
#if __has_builtin(__builtin_amdgcn_exp2f)
    return __builtin_amdgcn_exp2f(x);
#else
    float r; asm volatile("v_exp_f32 %0, %1" : "=v"(r) : "v"(x)); return r;
#endif
}

// Fragment-ready layout: for rowgroup rg = row/16, ks = k/32:
//   flat elem index = (rg*2 + ks)*512 + ((k%32)/8)*128 + (row%16)*8 + (k%8)
// A wave's MFMA fragment load for (rg, ks) is xf_base + lane*8 elems --
// one contiguous 1 KB burst per instruction.
//
// ws layout:
//   [0]        float sq2[8192]     (L2E * ||x_i||^2)
//   [+32KB]    short xf[8192*64]   (1 MB, fragment-tiled bf16)
//   [+32KB+1MB]float p1[1040]; float p3[256]

__global__ __launch_bounds__(256) void prep_kernel(const float* __restrict__ x,
                                                   float* __restrict__ sq2,
                                                   short* __restrict__ xf,
                                                   float* __restrict__ p3) {
    const int tid = threadIdx.x;
    const int r   = tid >> 3;           // 0..31 row within block
    const int ch  = tid & 7;            // 0..7, 8-element k-chunk
    const int row = blockIdx.x * 32 + r;

    const float4 u = *(const float4*)(x + (size_t)row * DD + ch * 8);
    const float4 v = *(const float4*)(x + (size_t)row * DD + ch * 8 + 4);
    short8 s8;
    s8[0] = __builtin_bit_cast(short, __float2bfloat16(u.x));
    s8[1] = __builtin_bit_cast(short, __float2bfloat16(u.y));
    s8[2] = __builtin_bit_cast(short, __float2bfloat16(u.z));
    s8[3] = __builtin_bit_cast(short, __float2bfloat16(u.w));
    s8[4] = __builtin_bit_cast(short, __float2bfloat16(v.x));
    s8[5] = __builtin_bit_cast(short, __float2bfloat16(v.y));
    s8[6] = __builtin_bit_cast(short, __float2bfloat16(v.z));
    s8[7] = __builtin_bit_cast(short, __float2bfloat16(v.w));

    const size_t F = (size_t)(row >> 4) * 1024 + (size_t)(ch >> 2) * 512
                   + (size_t)(ch & 3) * 128 + (size_t)(row & 15) * 8;
    *(short8*)(xf + F) = s8;

    float s = u.x*u.x + u.y*u.y + u.z*u.z + u.w*u.w
            + v.x*v.x + v.y*v.y + v.z*v.z + v.w*v.w;
    s += __shfl_xor(s, 1, 64);
    s += __shfl_xor(s, 2, 64);
    s += __shfl_xor(s, 4, 64);

    __shared__ float e3[32];
    if (ch == 0) {
        sq2[row] = L2E * s;
        e3[r] = __expf(s);
    }
    __syncthreads();
    if (tid == 0) {
        float t = 0.f;
        #pragma unroll
        for (int i = 0; i < 32; i++) t += e3[i];
        p3[blockIdx.x] = t;
    }
}

// 512 threads = 8 waves; waves 0-3 own tile 2s, waves 4-7 own tile 2s+1.
// Two-half MFMA/epilogue split keeps peak regs <=128 so 2 blocks/CU fit
// (launch_bounds(512,4) = 4 waves/SIMD). Per-wave work identical to R12.
__global__ __launch_bounds__(512, 4) void mmd_main(const short* __restrict__ xf,
                                                   const float* __restrict__ sq2,
                                                   float* __restrict__ p1) {
    const int s = (blockIdx.x % NXCD) * (NPAIR / NXCD) + blockIdx.x / NXCD;

    const int wid  = threadIdx.x >> 6;          // 0..7
    const int lane = threadIdx.x & 63;
    const int k = s * 2 + (wid >> 2);           // this wave's tile
    const int quad = wid & 3;
    const int wr = quad >> 1, wc = quad & 1;    // 64x64 quadrant within 128x128

    // linear upper-tri index -> (tr, tc), tr <= tc
    int tr = (int)((129.0f - sqrtf(16641.0f - 8.0f * (float)k)) * 0.5f);
    while (tr * NTILE - tr * (tr - 1) / 2 > k) --tr;
    while ((tr + 1) * NTILE - (tr + 1) * tr / 2 <= k) ++tr;
    const int tc = tr + (k - (tr * NTILE - tr * (tr - 1) / 2));
    const float w = (tc == tr) ? 1.0f : 2.0f;

    const int crow0 = (lane >> 4) * 4;          // C/D: row=(lane>>4)*4+reg, col=lane&15
    const int ccol  = lane & 15;

    const short* baseA = xf + (size_t)(tr * 16 + wr * 8) * 512 + lane * 8;
    const short* baseB = xf + (size_t)(tc * 16 + wc * 8) * 512 + lane * 8;

    // A fragments (live across both halves) + first-half B fragments
    short8 a[2][4], b0[2][2];
    #pragma unroll
    for (int ks = 0; ks < 2; ks++)
        #pragma unroll
        for (int m = 0; m < 4; m++)
            a[ks][m] = *(const short8*)(baseA + (m * 2 + ks) * 512);
    #pragma unroll
    for (int ks = 0; ks < 2; ks++)
        #pragma unroll
        for (int n = 0; n < 2; n++)
            b0[ks][n] = *(const short8*)(baseB + (n * 2 + ks) * 512);

    const int brow = tr * 128 + wr * 64;
    const int bcol = tc * 128 + wc * 64;
    float sqrl[16];
    #pragma unroll
    for (int m = 0; m < 4; m++) {
        const float4 f = *(const float4*)(sq2 + brow + m * 16 + crow0);
        sqrl[4*m+0] = f.x; sqrl[4*m+1] = f.y; sqrl[4*m+2] = f.z; sqrl[4*m+3] = f.w;
    }
    float sqcl[4];
    #pragma unroll
    for (int n = 0; n < 4; n++)
        sqcl[n] = sq2[bcol + n * 16 + ccol];

    float acc4[4] = {0.f, 0.f, 0.f, 0.f};

    // ---- half 1: n = 0,1 ----
    f32x4 c0[4][2];
    #pragma unroll
    for (int m = 0; m < 4; m++)
        #pragma unroll
        for (int n = 0; n < 2; n++)
            c0[m][n] = (f32x4){0.f, 0.f, 0.f, 0.f};
    #pragma unroll
    for (int ks = 0; ks < 2; ks++)
        #pragma unroll
        for (int m = 0; m < 4; m++)
            #pragma unroll
            for (int n = 0; n < 2; n++)
                c0[m][n] = __builtin_amdgcn_mfma_f32_16x16x32_bf16(a[ks][m], b0[ks][n], c0[m][n], 0, 0, 0);

    // issue second-half B loads; epilogue-1's exp chain covers their latency
    short8 b1[2][2];
    #pragma unroll
    for (int ks = 0; ks < 2; ks++)
        #pragma unroll
        for (int n = 0; n < 2; n++)
            b1[ks][n] = *(const short8*)(baseB + ((n + 2) * 2 + ks) * 512);

    #pragma unroll
    for (int n = 0; n < 2; n++)
        #pragma unroll
        for (int m = 0; m < 4; m++)
            #pragma unroll
            for (int r = 0; r < 4; r++)
                acc4[r] += fast_exp2(fmaf(-2.0f * L2E, c0[m][n][r], sqrl[m * 4 + r] + sqcl[n]));

    // ---- half 2: n = 2,3 ----
    f32x4 c1[4][2];
    #pragma unroll
    for (int m = 0; m < 4; m++)
        #pragma unroll
        for (int n = 0; n < 2; n++)
            c1[m][n] = (f32x4){0.f, 0.f, 0.f, 0.f};
    #pragma unroll
    for (int ks = 0; ks < 2; ks++)
        #pragma unroll
        for (int m = 0; m < 4; m++)
            #pragma unroll
            for (int n = 0; n < 2; n++)
                c1[m][n] = __builtin_amdgcn_mfma_f32_16x16x32_bf16(a[ks][m], b1[ks][n], c1[m][n], 0, 0, 0);

    #pragma unroll
    for (int n = 0; n < 2; n++)
        #pragma unroll
        for (int m = 0; m < 4; m++)
            #pragma unroll
            for (int r = 0; r < 4; r++)
                acc4[r] += fast_exp2(fmaf(-2.0f * L2E, c1[m][n][r], sqrl[m * 4 + r] + sqcl[n + 2]));

    float local = ((acc4[0] + acc4[1]) + (acc4[2] + acc4[3])) * w;
    #pragma unroll
    for (int off = 32; off; off >>= 1) local += __shfl_down(local, off, 64);
    __shared__ float red[8];
    if (lane == 0) red[wid] = local;
    __syncthreads();
    if (threadIdx.x == 0) {
        float t = 0.f;
        #pragma unroll
        for (int i = 0; i < 8; i++) t += red[i];
        p1[s] = t;
    }
}

__global__ void finalize_kernel(const float* __restrict__ p1, const float* __restrict__ p3,
                                float* __restrict__ out) {
    const int lane = threadIdx.x & 63;
    const int wid  = threadIdx.x >> 6;
    float s1 = 0.f, s3 = 0.f;
    for (int i = threadIdx.x; i < NPAIR; i += 256) s1 += p1[i];
    for (int i = threadIdx.x; i < NPREP; i += 256) s3 += p3[i];
    #pragma unroll
    for (int off = 32; off; off >>= 1) {
        s1 += __shfl_down(s1, off, 64);
        s3 += __shfl_down(s3, off, 64);
    }
    __shared__ float r1[4], r3[4];
    if (lane == 0) { r1[wid] = s1; r3[wid] = s3; }
    __syncthreads();
    if (threadIdx.x == 0) {
        const float t1 = (r1[0] + r1[1] + r1[2] + r1[3]) / ((float)TT * (float)TT);
        const float t3 = (r3[0] + r3[1] + r3[2] + r3[3]) / (float)TT;
        out[0] = t1 + 1.0f + t3;
    }
}

extern "C" void kernel_launch(void* const* d_in, const int* in_sizes, int n_in,
                              void* d_out, int out_size, void* d_ws, size_t ws_size,
                              hipStream_t stream) {
    const float* x = (const float*)d_in[0];   // xs: [4, 8192, 64] f32; only batch 0 used
    float* out = (float*)d_out;
    char* ws = (char*)d_ws;

    float* sq2 = (float*)ws;
    short* xf = (short*)(ws + TT * sizeof(float));
    float* p1 = (float*)(ws + TT * sizeof(float) + (size_t)TT * DD * sizeof(short));
    float* p3 = p1 + NPAIR;

    prep_kernel<<<NPREP, 256, 0, stream>>>(x, sq2, xf, p3);
    mmd_main<<<NPAIR, 512, 0, stream>>>(xf, sq2, p1);
    finalize_kernel<<<1, 256, 0, stream>>>(p1, p3, out);
}